// Round 1
// baseline (1380.858 us; speedup 1.0000x reference)
//
#include <hip/hip_runtime.h>
#include <cmath>

// Problem constants (from reference setup_inputs)
constexpr int T_   = 8;
constexpr int N_   = 8192;
constexpr int DEG_ = 15;
constexpr int E_   = N_ * (DEG_ + 1);   // 131072 edges per timestep
// H = 4 heads; HC = H*cout; C = HC/4 per head.

__device__ __forceinline__ float elu1(float v) { return v > 0.f ? v : expm1f(v); }

// ---------------------------------------------------------------------------
// GEMM: C[M,Ncol] = A[M,K] @ B[K,Ncol], fp32, batched over grid.z.
// z < nt  -> B = Bl, C = Cl + t*M*Ncol   (t = z)
// z >= nt -> B = Br, C = Cr + t*M*Ncol   (t = z - nt)
// A is offset by t*M*K.
// EPI: 0 = none, 1 = +bias then tanh, 2 = +bias
// Tile: BM=BN=64, BK=16, 256 threads, 4x4 per thread.
// ---------------------------------------------------------------------------
template<int EPI>
__global__ __launch_bounds__(256) void gemm_k(
    const float* __restrict__ A, const float* __restrict__ Bl, const float* __restrict__ Br,
    float* __restrict__ Cl, float* __restrict__ Cr, const float* __restrict__ bias,
    int M, int Ncol, int K, int nt)
{
  const int z = blockIdx.z;
  const int t = (z < nt) ? z : z - nt;
  const float* __restrict__ B = (z < nt) ? Bl : Br;
  float* __restrict__ C = ((z < nt) ? Cl : Cr) + (size_t)t * (size_t)M * Ncol;
  const float* __restrict__ Ab = A + (size_t)t * (size_t)M * K;

  __shared__ float As[16][68];   // [k][m], pad 68 -> 2-way max on scatter writes (free)
  __shared__ float Bs[16][64];   // [k][n]

  const int tid = threadIdx.x;
  const int tx = tid & 15, ty = tid >> 4;
  const int bm = blockIdx.x * 64, bn = blockIdx.y * 64;

  const int arow = tid >> 2;          // 0..63
  const int akc  = (tid & 3) * 4;     // 0,4,8,12
  const int brow = tid >> 4;          // 0..15
  const int bc4  = (tid & 15) * 4;    // 0..60

  float acc[4][4];
  #pragma unroll
  for (int i = 0; i < 4; i++)
    #pragma unroll
    for (int j = 0; j < 4; j++) acc[i][j] = 0.f;

  for (int k0 = 0; k0 < K; k0 += 16) {
    const float4 va = *(const float4*)(Ab + (size_t)(bm + arow) * K + (k0 + akc));
    const float4 vb = *(const float4*)(B  + (size_t)(k0 + brow) * Ncol + (bn + bc4));
    As[akc + 0][arow] = va.x;
    As[akc + 1][arow] = va.y;
    As[akc + 2][arow] = va.z;
    As[akc + 3][arow] = va.w;
    *(float4*)&Bs[brow][bc4] = vb;
    __syncthreads();
    #pragma unroll
    for (int kk = 0; kk < 16; kk++) {
      const float4 av = *(const float4*)&As[kk][ty * 4];
      const float4 bv = *(const float4*)&Bs[kk][tx * 4];
      const float a4[4] = {av.x, av.y, av.z, av.w};
      const float b4[4] = {bv.x, bv.y, bv.z, bv.w};
      #pragma unroll
      for (int i = 0; i < 4; i++)
        #pragma unroll
        for (int j = 0; j < 4; j++)
          acc[i][j] = fmaf(a4[i], b4[j], acc[i][j]);
    }
    __syncthreads();
  }

  #pragma unroll
  for (int i = 0; i < 4; i++) {
    const int row = bm + ty * 4 + i;
    const int col = bn + tx * 4;
    float v[4] = {acc[i][0], acc[i][1], acc[i][2], acc[i][3]};
    if (EPI >= 1) {
      #pragma unroll
      for (int j = 0; j < 4; j++) v[j] += bias[col + j];
      if (EPI == 1) {
        #pragma unroll
        for (int j = 0; j < 4; j++) v[j] = tanhf(v[j]);
      }
    }
    *(float4*)(C + (size_t)row * Ncol + col) = make_float4(v[0], v[1], v[2], v[3]);
  }
}

// ---------------------------------------------------------------------------
// GATv2 aggregation. One wave per node. Lane l owns channels [l*LPC,(l+1)*LPC)
// of the HC = H*C flattened (h,c) layout; 16-lane groups == one head.
// Online softmax over the 16 incoming edges (15 from edge_src + self loop).
// Epilogue: per-head normalize, cross-head mean (shfl_xor 16/32), +bias, ELU.
// CONCAT: out row has stride 2C; lanes 16..31 write elu(csrc) into [C,2C).
// ---------------------------------------------------------------------------
template<int HC, bool CONCAT>
__global__ __launch_bounds__(256) void gat_agg(
    const float* __restrict__ GL, const float* __restrict__ GR,
    const float* __restrict__ aw_, const float* __restrict__ bias,
    const int* __restrict__ esrc,       // base already offset to chunk start
    float* __restrict__ out,
    const float* __restrict__ csrc,     // [nodes][C] residual source (re-ELU'd), or null
    int numNodes)
{
  constexpr int C    = HC / 4;
  constexpr int LPC  = HC / 64;
  constexpr int OSTR = CONCAT ? 2 * C : C;

  const int lane = threadIdx.x & 63;
  const int wid  = threadIdx.x >> 6;
  const int gid  = blockIdx.x * 4 + wid;
  if (gid >= numNodes) return;
  const int t = gid >> 13;      // / N_
  const int i = gid & (N_ - 1);

  const float* __restrict__ gl = GL + (size_t)t * N_ * HC;
  const int*   __restrict__ es = esrc + (size_t)t * E_ + (size_t)i * DEG_;

  float gr[LPC], aw[LPC];
  {
    const float* grp = GR + (size_t)gid * HC + lane * LPC;
    const float* ap  = aw_ + lane * LPC;
    #pragma unroll
    for (int u = 0; u < LPC; u += 4) {
      const float4 g  = *(const float4*)(grp + u);
      const float4 a4 = *(const float4*)(ap + u);
      gr[u] = g.x; gr[u + 1] = g.y; gr[u + 2] = g.z; gr[u + 3] = g.w;
      aw[u] = a4.x; aw[u + 1] = a4.y; aw[u + 2] = a4.z; aw[u + 3] = a4.w;
    }
  }

  int js[16];
  #pragma unroll
  for (int k = 0; k < DEG_; k++) js[k] = es[k];
  js[DEG_] = i;   // self loop

  float m = -1e30f, den = 0.f;
  float acc[LPC];
  #pragma unroll
  for (int u = 0; u < LPC; u++) acc[u] = 0.f;

  for (int k = 0; k < 16; k++) {
    const float* glp = gl + (size_t)js[k] * HC + lane * LPC;
    float g[LPC];
    #pragma unroll
    for (int u = 0; u < LPC; u += 4) {
      const float4 v = *(const float4*)(glp + u);
      g[u] = v.x; g[u + 1] = v.y; g[u + 2] = v.z; g[u + 3] = v.w;
    }
    float p = 0.f;
    #pragma unroll
    for (int u = 0; u < LPC; u++) {
      float zz = g[u] + gr[u];
      zz = (zz > 0.f) ? zz : 0.2f * zz;   // LeakyReLU(0.2)
      p = fmaf(zz, aw[u], p);
    }
    // reduce within 16-lane head group (bit-identical on all lanes)
    p += __shfl_xor(p, 1);
    p += __shfl_xor(p, 2);
    p += __shfl_xor(p, 4);
    p += __shfl_xor(p, 8);

    const float nm    = fmaxf(m, p);
    const float scale = expf(m - nm);   // 0 on first iter (m = -1e30)
    const float w     = expf(p - nm);
    den = den * scale + w;
    #pragma unroll
    for (int u = 0; u < LPC; u++) acc[u] = acc[u] * scale + w * g[u];
    m = nm;
  }

  const float inv = 1.f / den;          // per-head normalizer
  #pragma unroll
  for (int u = 0; u < LPC; u++) acc[u] *= inv;
  // cross-head sum: lanes l, l^16, l^32, l^48 hold the same c-offset
  #pragma unroll
  for (int u = 0; u < LPC; u++) {
    acc[u] += __shfl_xor(acc[u], 16);
    acc[u] += __shfl_xor(acc[u], 32);
  }

  float* orow = out + (size_t)gid * OSTR;
  if (lane < 16) {
    #pragma unroll
    for (int u = 0; u < LPC; u++) {
      const int c = lane * LPC + u;
      acc[u] = elu1(acc[u] * 0.25f + bias[c]);
    }
    #pragma unroll
    for (int u = 0; u < LPC; u += 4)
      *(float4*)(orow + lane * LPC + u) = make_float4(acc[u], acc[u + 1], acc[u + 2], acc[u + 3]);
  } else if (CONCAT && lane < 32) {
    const int q = lane - 16;
    const float* cs = csrc + (size_t)gid * C + q * LPC;
    #pragma unroll
    for (int u = 0; u < LPC; u += 4) {
      const float4 v = *(const float4*)(cs + u);
      *(float4*)(orow + C + q * LPC + u) =
          make_float4(elu1(v.x), elu1(v.y), elu1(v.z), elu1(v.w));
    }
  }
}

// ---------------------------------------------------------------------------
extern "C" void kernel_launch(void* const* d_in, const int* in_sizes, int n_in,
                              void* d_out, int out_size, void* d_ws, size_t ws_size,
                              hipStream_t stream)
{
  (void)in_sizes; (void)n_in; (void)out_size; (void)ws_size;

  const float* x  = (const float*)d_in[0];
  const int*   es = (const int*)d_in[1];
  // d_in[2] = edge_dst: structure is fixed (repeat(arange,15) ++ arange) -> unused
  const float *c1_wl=(const float*)d_in[3], *c1_wr=(const float*)d_in[4], *c1_a=(const float*)d_in[5], *c1_b=(const float*)d_in[6];
  const float *c2_wl=(const float*)d_in[7], *c2_wr=(const float*)d_in[8], *c2_a=(const float*)d_in[9], *c2_b=(const float*)d_in[10];
  const float *c3_wl=(const float*)d_in[11],*c3_wr=(const float*)d_in[12],*c3_a=(const float*)d_in[13],*c3_b=(const float*)d_in[14];
  const float *c4_wl=(const float*)d_in[15],*c4_wr=(const float*)d_in[16],*c4_a=(const float*)d_in[17],*c4_b=(const float*)d_in[18];
  const float *r11_wl=(const float*)d_in[19],*r11_wr=(const float*)d_in[20],*r11_a=(const float*)d_in[21],*r11_b=(const float*)d_in[22];
  const float *r12_wl=(const float*)d_in[23],*r12_wr=(const float*)d_in[24],*r12_a=(const float*)d_in[25],*r12_b=(const float*)d_in[26];
  const float *r2_wl=(const float*)d_in[27],*r2_wr=(const float*)d_in[28],*r2_a=(const float*)d_in[29],*r2_b=(const float*)d_in[30];
  const float *f11_wl=(const float*)d_in[31],*f11_wr=(const float*)d_in[32],*f11_a=(const float*)d_in[33],*f11_b=(const float*)d_in[34];
  const float *f2_wl=(const float*)d_in[35],*f2_wr=(const float*)d_in[36],*f2_a=(const float*)d_in[37],*f2_b=(const float*)d_in[38];
  const float *r3_w=(const float*)d_in[39], *r3_b=(const float*)d_in[40];
  const float *f3_w=(const float*)d_in[41], *f3_b=(const float*)d_in[42];
  const float *r4_w=(const float*)d_in[43], *r4_b=(const float*)d_in[44];
  const float *f4_w=(const float*)d_in[45], *f4_b=(const float*)d_in[46];

  // Workspace layout (floats). GL/GR sized 16 Mi floats (64 MB) each:
  //   c1 runs in 2 chunks of 4 timesteps (4*8192*512), other T-layers fit T*N*256.
  float* ws = (float*)d_ws;
  float* GL = ws;
  float* GR = GL + (size_t)16777216;
  float* A0 = GR + (size_t)16777216;            // [T,N,128] out1, later emb3
  float* A1 = A0 + (size_t)T_ * N_ * 128;       // [T,N,64]  emb2
  float* B0 = A1 + (size_t)T_ * N_ * 64;        // [N,128]
  float* B1 = B0 + (size_t)N_ * 128;            // [N,128]
  // total = 48,234,496 floats = ~184 MB

  float* recon = (float*)d_out;
  float* fcst  = recon + (size_t)N_ * 64;
  float* emb   = fcst + (size_t)N_ * 64;        // [T,N,64]

  const dim3 blk(256);

  // ---- c1: 64 -> 128 (HC=512), 2 chunks of 4 timesteps ----
  for (int ch = 0; ch < 2; ch++) {
    const int t0 = ch * 4, nt = 4;
    gemm_k<0><<<dim3(N_ / 64, 512 / 64, 2 * nt), blk, 0, stream>>>(
        x + (size_t)t0 * N_ * 64, c1_wl, c1_wr, GL, GR, nullptr, N_, 512, 64, nt);
    gat_agg<512, false><<<dim3(nt * N_ / 4), blk, 0, stream>>>(
        GL, GR, c1_a, c1_b, es + (size_t)t0 * E_, A0 + (size_t)t0 * N_ * 128, nullptr, nt * N_);
  }
  // ---- c2: 128 -> 64 (HC=256) ----
  gemm_k<0><<<dim3(N_ / 64, 256 / 64, 2 * T_), blk, 0, stream>>>(
      A0, c2_wl, c2_wr, GL, GR, nullptr, N_, 256, 128, T_);
  gat_agg<256, false><<<dim3(T_ * N_ / 4), blk, 0, stream>>>(
      GL, GR, c2_a, c2_b, es, A1, nullptr, T_ * N_);
  // ---- c3: 64 -> 64 (HC=256), concat with elu(emb2) ----
  gemm_k<0><<<dim3(N_ / 64, 256 / 64, 2 * T_), blk, 0, stream>>>(
      A1, c3_wl, c3_wr, GL, GR, nullptr, N_, 256, 64, T_);
  gat_agg<256, true><<<dim3(T_ * N_ / 4), blk, 0, stream>>>(
      GL, GR, c3_a, c3_b, es, A0, A1, T_ * N_);
  // ---- c4: 128 -> 64 (HC=256) -> emb (final output region) ----
  gemm_k<0><<<dim3(N_ / 64, 256 / 64, 2 * T_), blk, 0, stream>>>(
      A0, c4_wl, c4_wr, GL, GR, nullptr, N_, 256, 128, T_);
  gat_agg<256, false><<<dim3(T_ * N_ / 4), blk, 0, stream>>>(
      GL, GR, c4_a, c4_b, es, emb, nullptr, T_ * N_);

  // ---- reconstruction branch (edges at t = 7) ----
  const float* embR = emb + (size_t)7 * N_ * 64;
  const int*   esR  = es + (size_t)7 * E_;
  gemm_k<0><<<dim3(N_ / 64, 4, 2), blk, 0, stream>>>(embR, r11_wl, r11_wr, GL, GR, nullptr, N_, 256, 64, 1);
  gat_agg<256, false><<<dim3(N_ / 4), blk, 0, stream>>>(GL, GR, r11_a, r11_b, esR, B0, nullptr, N_);
  gemm_k<0><<<dim3(N_ / 64, 4, 2), blk, 0, stream>>>(B0, r12_wl, r12_wr, GL, GR, nullptr, N_, 256, 64, 1);
  gat_agg<256, true><<<dim3(N_ / 4), blk, 0, stream>>>(GL, GR, r12_a, r12_b, esR, B1, B0, N_);
  gemm_k<0><<<dim3(N_ / 64, 8, 2), blk, 0, stream>>>(B1, r2_wl, r2_wr, GL, GR, nullptr, N_, 512, 128, 1);
  gat_agg<512, false><<<dim3(N_ / 4), blk, 0, stream>>>(GL, GR, r2_a, r2_b, esR, B0, nullptr, N_);
  gemm_k<1><<<dim3(N_ / 64, 1, 1), blk, 0, stream>>>(B0, r3_w, r3_w, B1, B1, r3_b, N_, 64, 128, 1);
  gemm_k<2><<<dim3(N_ / 64, 1, 1), blk, 0, stream>>>(B1, r4_w, r4_w, recon, recon, r4_b, N_, 64, 64, 1);

  // ---- forecasting branch (edges at t = 6; concat layer reuses r12 weights) ----
  const float* embF = emb + (size_t)6 * N_ * 64;
  const int*   esF  = es + (size_t)6 * E_;
  gemm_k<0><<<dim3(N_ / 64, 4, 2), blk, 0, stream>>>(embF, f11_wl, f11_wr, GL, GR, nullptr, N_, 256, 64, 1);
  gat_agg<256, false><<<dim3(N_ / 4), blk, 0, stream>>>(GL, GR, f11_a, f11_b, esF, B0, nullptr, N_);
  gemm_k<0><<<dim3(N_ / 64, 4, 2), blk, 0, stream>>>(B0, r12_wl, r12_wr, GL, GR, nullptr, N_, 256, 64, 1);
  gat_agg<256, true><<<dim3(N_ / 4), blk, 0, stream>>>(GL, GR, r12_a, r12_b, esF, B1, B0, N_);
  gemm_k<0><<<dim3(N_ / 64, 8, 2), blk, 0, stream>>>(B1, f2_wl, f2_wr, GL, GR, nullptr, N_, 512, 128, 1);
  gat_agg<512, false><<<dim3(N_ / 4), blk, 0, stream>>>(GL, GR, f2_a, f2_b, esF, B0, nullptr, N_);
  gemm_k<1><<<dim3(N_ / 64, 1, 1), blk, 0, stream>>>(B0, f3_w, f3_w, B1, B1, f3_b, N_, 64, 128, 1);
  gemm_k<2><<<dim3(N_ / 64, 1, 1), blk, 0, stream>>>(B1, f4_w, f4_w, fcst, fcst, f4_b, N_, 64, 64, 1);
}

// Round 2
// 1313.711 us; speedup vs baseline: 1.0511x; 1.0511x over previous
//
#include <hip/hip_runtime.h>
#include <cmath>

// Problem constants (from reference setup_inputs)
constexpr int T_   = 8;
constexpr int N_   = 8192;
constexpr int DEG_ = 15;
constexpr int E_   = N_ * (DEG_ + 1);   // 131072 edges per timestep

__device__ __forceinline__ float elu1(float v) { return v > 0.f ? v : expm1f(v); }

// ---------------------------------------------------------------------------
// Big GEMM: C[M,Ncol] = A[M,K] @ B[K,Ncol], fp32, batched over grid.z.
// z < nt -> B=Bl, C=Cl+t*M*Ncol ; z>=nt -> B=Br, C=Cr+t*M*Ncol (t=z-nt)
// Tile: BM=128, BN=64, BK=16, 256 threads, 8x4 per thread.
// Requires M%128==0, Ncol%64==0, K%16==0.
// ---------------------------------------------------------------------------
template<int EPI>   // 0 none, 1 +bias tanh, 2 +bias
__global__ __launch_bounds__(256) void gemm_big(
    const float* __restrict__ A, const float* __restrict__ Bl, const float* __restrict__ Br,
    float* __restrict__ Cl, float* __restrict__ Cr, const float* __restrict__ bias,
    int M, int Ncol, int K, int nt)
{
  const int z = blockIdx.z;
  const int t = (z < nt) ? z : z - nt;
  const float* __restrict__ B = (z < nt) ? Bl : Br;
  float* __restrict__ C = ((z < nt) ? Cl : Cr) + (size_t)t * (size_t)M * Ncol;
  const float* __restrict__ Ab = A + (size_t)t * (size_t)M * K;

  __shared__ float As[16][132];   // [k][m] transposed, padded
  __shared__ float Bs[16][64];    // [k][n]

  const int tid = threadIdx.x;
  const int tx = tid & 15;        // col group (4 cols)
  const int ty = tid >> 4;        // row group (8 rows)
  const int bm = blockIdx.x * 128, bn = blockIdx.y * 64;

  const int arow = tid >> 1;          // 0..127
  const int akc  = (tid & 1) * 8;     // 0 or 8
  const int brow = tid >> 4;          // 0..15
  const int bc4  = (tid & 15) * 4;    // 0..60

  float acc[8][4];
  #pragma unroll
  for (int i = 0; i < 8; i++)
    #pragma unroll
    for (int j = 0; j < 4; j++) acc[i][j] = 0.f;

  for (int k0 = 0; k0 < K; k0 += 16) {
    const float4 va0 = *(const float4*)(Ab + (size_t)(bm + arow) * K + (k0 + akc));
    const float4 va1 = *(const float4*)(Ab + (size_t)(bm + arow) * K + (k0 + akc + 4));
    const float4 vb  = *(const float4*)(B  + (size_t)(k0 + brow) * Ncol + (bn + bc4));
    As[akc + 0][arow] = va0.x; As[akc + 1][arow] = va0.y;
    As[akc + 2][arow] = va0.z; As[akc + 3][arow] = va0.w;
    As[akc + 4][arow] = va1.x; As[akc + 5][arow] = va1.y;
    As[akc + 6][arow] = va1.z; As[akc + 7][arow] = va1.w;
    *(float4*)&Bs[brow][bc4] = vb;
    __syncthreads();
    #pragma unroll
    for (int kk = 0; kk < 16; kk++) {
      const float4 a0 = *(const float4*)&As[kk][ty * 8];
      const float4 a1 = *(const float4*)&As[kk][ty * 8 + 4];
      const float4 bv = *(const float4*)&Bs[kk][tx * 4];
      const float a8[8] = {a0.x, a0.y, a0.z, a0.w, a1.x, a1.y, a1.z, a1.w};
      const float b4[4] = {bv.x, bv.y, bv.z, bv.w};
      #pragma unroll
      for (int i = 0; i < 8; i++)
        #pragma unroll
        for (int j = 0; j < 4; j++)
          acc[i][j] = fmaf(a8[i], b4[j], acc[i][j]);
    }
    __syncthreads();
  }

  #pragma unroll
  for (int i = 0; i < 8; i++) {
    const int row = bm + ty * 8 + i;
    const int col = bn + tx * 4;
    float v[4] = {acc[i][0], acc[i][1], acc[i][2], acc[i][3]};
    if (EPI >= 1) {
      #pragma unroll
      for (int j = 0; j < 4; j++) v[j] += bias[col + j];
      if (EPI == 1) {
        #pragma unroll
        for (int j = 0; j < 4; j++) v[j] = tanhf(v[j]);
      }
    }
    *(float4*)(C + (size_t)row * Ncol + col) = make_float4(v[0], v[1], v[2], v[3]);
  }
}

// ---------------------------------------------------------------------------
// Small GEMM for the N=64 epilogue layers (64x64 tile, 4x4/thread).
// ---------------------------------------------------------------------------
template<int EPI>
__global__ __launch_bounds__(256) void gemm_k(
    const float* __restrict__ A, const float* __restrict__ B,
    float* __restrict__ C, const float* __restrict__ bias,
    int M, int Ncol, int K)
{
  __shared__ float As[16][68];
  __shared__ float Bs[16][64];

  const int tid = threadIdx.x;
  const int tx = tid & 15, ty = tid >> 4;
  const int bm = blockIdx.x * 64, bn = blockIdx.y * 64;

  const int arow = tid >> 2;
  const int akc  = (tid & 3) * 4;
  const int brow = tid >> 4;
  const int bc4  = (tid & 15) * 4;

  float acc[4][4];
  #pragma unroll
  for (int i = 0; i < 4; i++)
    #pragma unroll
    for (int j = 0; j < 4; j++) acc[i][j] = 0.f;

  for (int k0 = 0; k0 < K; k0 += 16) {
    const float4 va = *(const float4*)(A + (size_t)(bm + arow) * K + (k0 + akc));
    const float4 vb = *(const float4*)(B + (size_t)(k0 + brow) * Ncol + (bn + bc4));
    As[akc + 0][arow] = va.x; As[akc + 1][arow] = va.y;
    As[akc + 2][arow] = va.z; As[akc + 3][arow] = va.w;
    *(float4*)&Bs[brow][bc4] = vb;
    __syncthreads();
    #pragma unroll
    for (int kk = 0; kk < 16; kk++) {
      const float4 av = *(const float4*)&As[kk][ty * 4];
      const float4 bv = *(const float4*)&Bs[kk][tx * 4];
      const float a4[4] = {av.x, av.y, av.z, av.w};
      const float b4[4] = {bv.x, bv.y, bv.z, bv.w};
      #pragma unroll
      for (int i = 0; i < 4; i++)
        #pragma unroll
        for (int j = 0; j < 4; j++)
          acc[i][j] = fmaf(a4[i], b4[j], acc[i][j]);
    }
    __syncthreads();
  }

  #pragma unroll
  for (int i = 0; i < 4; i++) {
    const int row = bm + ty * 4 + i;
    const int col = bn + tx * 4;
    float v[4] = {acc[i][0], acc[i][1], acc[i][2], acc[i][3]};
    if (EPI >= 1) {
      #pragma unroll
      for (int j = 0; j < 4; j++) v[j] += bias[col + j];
      if (EPI == 1) {
        #pragma unroll
        for (int j = 0; j < 4; j++) v[j] = tanhf(v[j]);
      }
    }
    *(float4*)(C + (size_t)row * Ncol + col) = make_float4(v[0], v[1], v[2], v[3]);
  }
}

// ---------------------------------------------------------------------------
// GATv2 aggregation, latency-optimized: preload all 16 gathered rows into
// registers (MLP=16), two-pass softmax fully in registers.
// One wave per node; lane l owns channels [l*LPC,(l+1)*LPC); 16-lane group = head.
// HC=256: CH=1 chunk (g stays resident). HC=512: CH=2 chunks of 4 channels;
// score pass streams both chunks, message pass reuses last chunk from regs and
// reloads chunk 0 (L1/L2-hot).
// ---------------------------------------------------------------------------
template<int HC, bool CONCAT>
__global__ __launch_bounds__(256) void gat_agg(
    const float* __restrict__ GL, const float* __restrict__ GR,
    const float* __restrict__ aw_, const float* __restrict__ bias,
    const int* __restrict__ esrc, float* __restrict__ out,
    const float* __restrict__ csrc, int numNodes)
{
  constexpr int C    = HC / 4;
  constexpr int LPC  = HC / 64;
  constexpr int CH   = LPC / 4;     // channel chunks of 4
  constexpr int OSTR = CONCAT ? 2 * C : C;

  const int lane = threadIdx.x & 63;
  const int wid  = threadIdx.x >> 6;
  const int gid  = blockIdx.x * 4 + wid;
  if (gid >= numNodes) return;
  const int t = gid >> 13;
  const int i = gid & (N_ - 1);

  const float* __restrict__ gl = GL + (size_t)t * N_ * HC;
  const int*   __restrict__ es = esrc + (size_t)t * E_ + (size_t)i * DEG_;

  int js[16];
  #pragma unroll
  for (int k = 0; k < DEG_; k++) js[k] = es[k];
  js[DEG_] = i;

  float gr[LPC], aw[LPC];
  {
    const float* grp = GR + (size_t)gid * HC + lane * LPC;
    const float* ap  = aw_ + lane * LPC;
    #pragma unroll
    for (int u = 0; u < LPC; u += 4) {
      const float4 gv = *(const float4*)(grp + u);
      const float4 a4 = *(const float4*)(ap + u);
      gr[u] = gv.x; gr[u + 1] = gv.y; gr[u + 2] = gv.z; gr[u + 3] = gv.w;
      aw[u] = a4.x; aw[u + 1] = a4.y; aw[u + 2] = a4.z; aw[u + 3] = a4.w;
    }
  }

  float p[16];
  #pragma unroll
  for (int k = 0; k < 16; k++) p[k] = 0.f;

  float g[16][4];
  #pragma unroll
  for (int ch = 0; ch < CH; ch++) {
    // issue all 16 gather loads back-to-back
    #pragma unroll
    for (int k = 0; k < 16; k++) {
      const float4 v = *(const float4*)(gl + (size_t)js[k] * HC + lane * LPC + ch * 4);
      g[k][0] = v.x; g[k][1] = v.y; g[k][2] = v.z; g[k][3] = v.w;
    }
    #pragma unroll
    for (int k = 0; k < 16; k++) {
      #pragma unroll
      for (int u = 0; u < 4; u++) {
        float z = g[k][u] + gr[ch * 4 + u];
        z = (z > 0.f) ? z : 0.2f * z;          // LeakyReLU(0.2)
        p[k] = fmaf(z, aw[ch * 4 + u], p[k]);
      }
    }
  }

  // reduce scores within 16-lane head group (all lanes end with same value)
  #pragma unroll
  for (int k = 0; k < 16; k++) {
    p[k] += __shfl_xor(p[k], 1);
    p[k] += __shfl_xor(p[k], 2);
    p[k] += __shfl_xor(p[k], 4);
    p[k] += __shfl_xor(p[k], 8);
  }

  // two-pass softmax in registers
  float m = p[0];
  #pragma unroll
  for (int k = 1; k < 16; k++) m = fmaxf(m, p[k]);
  float den = 0.f;
  #pragma unroll
  for (int k = 0; k < 16; k++) { p[k] = expf(p[k] - m); den += p[k]; }
  const float inv = 1.f / den;

  // weighted message sum; last chunk still resident in g
  float acc[LPC];
  #pragma unroll
  for (int u = 0; u < 4; u++) {
    float s = 0.f;
    #pragma unroll
    for (int k = 0; k < 16; k++) s = fmaf(p[k], g[k][u], s);
    acc[(CH - 1) * 4 + u] = s;
  }
  #pragma unroll
  for (int ch = 0; ch < CH - 1; ch++) {
    float gg[16][4];
    #pragma unroll
    for (int k = 0; k < 16; k++) {
      const float4 v = *(const float4*)(gl + (size_t)js[k] * HC + lane * LPC + ch * 4);
      gg[k][0] = v.x; gg[k][1] = v.y; gg[k][2] = v.z; gg[k][3] = v.w;
    }
    #pragma unroll
    for (int u = 0; u < 4; u++) {
      float s = 0.f;
      #pragma unroll
      for (int k = 0; k < 16; k++) s = fmaf(p[k], gg[k][u], s);
      acc[ch * 4 + u] = s;
    }
  }

  #pragma unroll
  for (int u = 0; u < LPC; u++) acc[u] *= inv;
  // cross-head sum
  #pragma unroll
  for (int u = 0; u < LPC; u++) {
    acc[u] += __shfl_xor(acc[u], 16);
    acc[u] += __shfl_xor(acc[u], 32);
  }

  float* orow = out + (size_t)gid * OSTR;
  if (lane < 16) {
    #pragma unroll
    for (int u = 0; u < LPC; u++)
      acc[u] = elu1(acc[u] * 0.25f + bias[lane * LPC + u]);
    #pragma unroll
    for (int u = 0; u < LPC; u += 4)
      *(float4*)(orow + lane * LPC + u) = make_float4(acc[u], acc[u + 1], acc[u + 2], acc[u + 3]);
  } else if (CONCAT && lane < 32) {
    const int q = lane - 16;
    const float* cs = csrc + (size_t)gid * C + q * LPC;
    #pragma unroll
    for (int u = 0; u < LPC; u += 4) {
      const float4 v = *(const float4*)(cs + u);
      *(float4*)(orow + C + q * LPC + u) =
          make_float4(elu1(v.x), elu1(v.y), elu1(v.z), elu1(v.w));
    }
  }
}

// ---------------------------------------------------------------------------
extern "C" void kernel_launch(void* const* d_in, const int* in_sizes, int n_in,
                              void* d_out, int out_size, void* d_ws, size_t ws_size,
                              hipStream_t stream)
{
  (void)in_sizes; (void)n_in; (void)out_size; (void)ws_size;

  const float* x  = (const float*)d_in[0];
  const int*   es = (const int*)d_in[1];
  const float *c1_wl=(const float*)d_in[3], *c1_wr=(const float*)d_in[4], *c1_a=(const float*)d_in[5], *c1_b=(const float*)d_in[6];
  const float *c2_wl=(const float*)d_in[7], *c2_wr=(const float*)d_in[8], *c2_a=(const float*)d_in[9], *c2_b=(const float*)d_in[10];
  const float *c3_wl=(const float*)d_in[11],*c3_wr=(const float*)d_in[12],*c3_a=(const float*)d_in[13],*c3_b=(const float*)d_in[14];
  const float *c4_wl=(const float*)d_in[15],*c4_wr=(const float*)d_in[16],*c4_a=(const float*)d_in[17],*c4_b=(const float*)d_in[18];
  const float *r11_wl=(const float*)d_in[19],*r11_wr=(const float*)d_in[20],*r11_a=(const float*)d_in[21],*r11_b=(const float*)d_in[22];
  const float *r12_wl=(const float*)d_in[23],*r12_wr=(const float*)d_in[24],*r12_a=(const float*)d_in[25],*r12_b=(const float*)d_in[26];
  const float *r2_wl=(const float*)d_in[27],*r2_wr=(const float*)d_in[28],*r2_a=(const float*)d_in[29],*r2_b=(const float*)d_in[30];
  const float *f11_wl=(const float*)d_in[31],*f11_wr=(const float*)d_in[32],*f11_a=(const float*)d_in[33],*f11_b=(const float*)d_in[34];
  const float *f2_wl=(const float*)d_in[35],*f2_wr=(const float*)d_in[36],*f2_a=(const float*)d_in[37],*f2_b=(const float*)d_in[38];
  const float *r3_w=(const float*)d_in[39], *r3_b=(const float*)d_in[40];
  const float *f3_w=(const float*)d_in[41], *f3_b=(const float*)d_in[42];
  const float *r4_w=(const float*)d_in[43], *r4_b=(const float*)d_in[44];
  const float *f4_w=(const float*)d_in[45], *f4_b=(const float*)d_in[46];

  float* ws = (float*)d_ws;
  float* GL = ws;
  float* GR = GL + (size_t)16777216;
  float* A0 = GR + (size_t)16777216;            // [T,N,128]
  float* A1 = A0 + (size_t)T_ * N_ * 128;       // [T,N,64]
  float* B0 = A1 + (size_t)T_ * N_ * 64;        // [N,128]
  float* B1 = B0 + (size_t)N_ * 128;            // [N,128]

  float* recon = (float*)d_out;
  float* fcst  = recon + (size_t)N_ * 64;
  float* emb   = fcst + (size_t)N_ * 64;        // [T,N,64]

  const dim3 blk(256);

  // ---- c1: 64 -> 128 (HC=512), 2 chunks of 4 timesteps ----
  for (int ch = 0; ch < 2; ch++) {
    const int t0 = ch * 4, nt = 4;
    gemm_big<0><<<dim3(N_ / 128, 512 / 64, 2 * nt), blk, 0, stream>>>(
        x + (size_t)t0 * N_ * 64, c1_wl, c1_wr, GL, GR, nullptr, N_, 512, 64, nt);
    gat_agg<512, false><<<dim3(nt * N_ / 4), blk, 0, stream>>>(
        GL, GR, c1_a, c1_b, es + (size_t)t0 * E_, A0 + (size_t)t0 * N_ * 128, nullptr, nt * N_);
  }
  // ---- c2: 128 -> 64 (HC=256) ----
  gemm_big<0><<<dim3(N_ / 128, 256 / 64, 2 * T_), blk, 0, stream>>>(
      A0, c2_wl, c2_wr, GL, GR, nullptr, N_, 256, 128, T_);
  gat_agg<256, false><<<dim3(T_ * N_ / 4), blk, 0, stream>>>(
      GL, GR, c2_a, c2_b, es, A1, nullptr, T_ * N_);
  // ---- c3: 64 -> 64 (HC=256), concat with elu(emb2) ----
  gemm_big<0><<<dim3(N_ / 128, 256 / 64, 2 * T_), blk, 0, stream>>>(
      A1, c3_wl, c3_wr, GL, GR, nullptr, N_, 256, 64, T_);
  gat_agg<256, true><<<dim3(T_ * N_ / 4), blk, 0, stream>>>(
      GL, GR, c3_a, c3_b, es, A0, A1, T_ * N_);
  // ---- c4: 128 -> 64 (HC=256) -> emb ----
  gemm_big<0><<<dim3(N_ / 128, 256 / 64, 2 * T_), blk, 0, stream>>>(
      A0, c4_wl, c4_wr, GL, GR, nullptr, N_, 256, 128, T_);
  gat_agg<256, false><<<dim3(T_ * N_ / 4), blk, 0, stream>>>(
      GL, GR, c4_a, c4_b, es, emb, nullptr, T_ * N_);

  // ---- reconstruction branch (edges at t = 7) ----
  const float* embR = emb + (size_t)7 * N_ * 64;
  const int*   esR  = es + (size_t)7 * E_;
  gemm_big<0><<<dim3(N_ / 128, 4, 2), blk, 0, stream>>>(embR, r11_wl, r11_wr, GL, GR, nullptr, N_, 256, 64, 1);
  gat_agg<256, false><<<dim3(N_ / 4), blk, 0, stream>>>(GL, GR, r11_a, r11_b, esR, B0, nullptr, N_);
  gemm_big<0><<<dim3(N_ / 128, 4, 2), blk, 0, stream>>>(B0, r12_wl, r12_wr, GL, GR, nullptr, N_, 256, 64, 1);
  gat_agg<256, true><<<dim3(N_ / 4), blk, 0, stream>>>(GL, GR, r12_a, r12_b, esR, B1, B0, N_);
  gemm_big<0><<<dim3(N_ / 128, 8, 2), blk, 0, stream>>>(B1, r2_wl, r2_wr, GL, GR, nullptr, N_, 512, 128, 1);
  gat_agg<512, false><<<dim3(N_ / 4), blk, 0, stream>>>(GL, GR, r2_a, r2_b, esR, B0, nullptr, N_);
  gemm_k<1><<<dim3(N_ / 64, 1, 1), blk, 0, stream>>>(B0, r3_w, B1, r3_b, N_, 64, 128);
  gemm_k<2><<<dim3(N_ / 64, 1, 1), blk, 0, stream>>>(B1, r4_w, recon, r4_b, N_, 64, 64);

  // ---- forecasting branch (edges at t = 6; concat layer reuses r12 weights) ----
  const float* embF = emb + (size_t)6 * N_ * 64;
  const int*   esF  = es + (size_t)6 * E_;
  gemm_big<0><<<dim3(N_ / 128, 4, 2), blk, 0, stream>>>(embF, f11_wl, f11_wr, GL, GR, nullptr, N_, 256, 64, 1);
  gat_agg<256, false><<<dim3(N_ / 4), blk, 0, stream>>>(GL, GR, f11_a, f11_b, esF, B0, nullptr, N_);
  gemm_big<0><<<dim3(N_ / 128, 4, 2), blk, 0, stream>>>(B0, r12_wl, r12_wr, GL, GR, nullptr, N_, 256, 64, 1);
  gat_agg<256, true><<<dim3(N_ / 4), blk, 0, stream>>>(GL, GR, r12_a, r12_b, esF, B1, B0, N_);
  gemm_big<0><<<dim3(N_ / 128, 8, 2), blk, 0, stream>>>(B1, f2_wl, f2_wr, GL, GR, nullptr, N_, 512, 128, 1);
  gat_agg<512, false><<<dim3(N_ / 4), blk, 0, stream>>>(GL, GR, f2_a, f2_b, esF, B0, nullptr, N_);
  gemm_k<1><<<dim3(N_ / 64, 1, 1), blk, 0, stream>>>(B0, f3_w, B1, f3_b, N_, 64, 128);
  gemm_k<2><<<dim3(N_ / 64, 1, 1), blk, 0, stream>>>(B1, f4_w, fcst, f4_b, N_, 64, 64);
}